// Round 3
// baseline (17510.313 us; speedup 1.0000x reference)
//
#include <hip/hip_runtime.h>
#include <math.h>

#define NN 256
#define BB 1024
#define NMAT 1025   // 1024 batch matrices + 1 for L0

typedef float f32x32 __attribute__((ext_vector_type(32)));

// Static device storage (rewritten every launch)
__device__ float g_T[4][NN*NN];      // T[c][j*256+i] = Ws(i,j)*E(i,j,a,b)/(V[i][a]V[j][b]), c=2a+b
__device__ float g_Ws[NN*NN];        // Ws[j*256+i] (symmetric)
__device__ float g_V[NN][2];
__device__ float g_ld[NMAT];

__device__ __forceinline__ float sigmf(float v) { return 1.0f / (1.0f + expf(-v)); }

__global__ void k_prep_v(const float* __restrict__ Vc) {
  int i = threadIdx.x;
  float a = sigmf(Vc[2*i]);
  float b = sigmf(Vc[2*i+1]);
  float s = a + b;
  g_V[i][0] = a / s;
  g_V[i][1] = b / s;
}

__global__ void k_prep_T(const float* __restrict__ W, const float* __restrict__ lam) {
  int j = blockIdx.x;
  int i = threadIdx.x;
  float vi0 = g_V[i][0], vi1 = g_V[i][1];
  float vj0 = g_V[j][0], vj1 = g_V[j][1];
  float ws;
  if (i > j)      ws = sigmf(W[i*NN + j]);
  else if (i < j) ws = sigmf(W[j*NN + i]);
  else            ws = 0.0f;
  g_Ws[j*NN + i] = ws;
  float s = sigmf(lam[i*NN + j]);
  float pi = vi0, pj = vj0;
  float lower = fmaxf(1e-7f, pi + pj - 1.0f);
  float upper = fminf(pi, pj);
  float P00 = lower + s * (upper - lower);
  float P01 = pi - P00;
  float P10 = pj - P00;
  float P11 = 1.0f - pi - pj + P00;
  if (i == j) { P00 = P01 = P10 = P11 = 0.0f; }
  P00 = fminf(fmaxf(P00, 0.0f), 1.0f);
  P01 = fminf(fmaxf(P01, 0.0f), 1.0f);
  P10 = fminf(fmaxf(P10, 0.0f), 1.0f);
  P11 = fminf(fmaxf(P11, 0.0f), 1.0f);
  int o = j*NN + i;
  g_T[0][o] = ws * P00 / (vi0 * vj0);
  g_T[1][o] = ws * P01 / (vi0 * vj1);
  g_T[2][o] = ws * P10 / (vi1 * vj0);
  g_T[3][o] = ws * P11 / (vi1 * vj1);
}

// ---------- macro helpers (all vector indices are literals) ----------

// build one column (literal cc) for the batch path
#define BCOLT(cc) { \
  const int gc = (G<<5) + (cc); \
  const int gcn = (gc + 1) & 255; \
  const int off = xs[gcn]*(NN*NN) + (gcn<<8); \
  float w0=b0[off], w1=b1[off], w2=b2[off], w3=b3[off]; \
  float w4=b4[off], w5=b5[off], w6=b6[off], w7=b7[off]; \
  if ((cc)==31) { if (G==7) { w0=0;w1=0;w2=0;w3=0;w4=0;w5=0;w6=0;w7=0; } } \
  s0+=w0; s1+=w1; s2+=w2; s3+=w3; s4+=w4; s5+=w5; s6+=w6; s7+=w7; \
  v0[(cc)]=-w0; v1[(cc)]=-w1; v2[(cc)]=-w2; v3[(cc)]=-w3; \
  v4[(cc)]=-w4; v5[(cc)]=-w5; v6[(cc)]=-w6; v7[(cc)]=-w7; }

// build one column (literal cc) for the L0 path
#define BCOLW(cc) { \
  const int gc = (G<<5) + (cc); \
  const int gcn = (gc + 1) & 255; \
  const int off = (gcn<<8); \
  float w0=b0[off], w1=b1[off], w2=b2[off], w3=b3[off]; \
  float w4=b4[off], w5=b5[off], w6=b6[off], w7=b7[off]; \
  if ((cc)==31) { if (G==7) { w0=0;w1=0;w2=0;w3=0;w4=0;w5=0;w6=0;w7=0; } } \
  s0+=w0; s1+=w1; s2+=w2; s3+=w3; s4+=w4; s5+=w5; s6+=w6; s7+=w7; \
  v0[(cc)]=-w0; v1[(cc)]=-w1; v2[(cc)]=-w2; v3[(cc)]=-w3; \
  v4[(cc)]=-w4; v5[(cc)]=-w5; v6[(cc)]=-w6; v7[(cc)]=-w7; }

#define B4(M,c) M(c) M((c)+1) M((c)+2) M((c)+3)
#define B16(M,c) B4(M,c) B4(M,(c)+4) B4(M,(c)+8) B4(M,(c)+12)
#define B32(M) B16(M,0) B16(M,16)

// select row-vector by literal row index (0..7)
#define URSEL(KP) { \
  if constexpr (((KP)&7)==0) urow[(KP)&1][G] = v0; \
  else if constexpr (((KP)&7)==1) urow[(KP)&1][G] = v1; \
  else if constexpr (((KP)&7)==2) urow[(KP)&1][G] = v2; \
  else if constexpr (((KP)&7)==3) urow[(KP)&1][G] = v3; \
  else if constexpr (((KP)&7)==4) urow[(KP)&1][G] = v4; \
  else if constexpr (((KP)&7)==5) urow[(KP)&1][G] = v5; \
  else if constexpr (((KP)&7)==6) urow[(KP)&1][G] = v6; \
  else urow[(KP)&1][G] = v7; }

#define PIVSEL(KP) ( \
  ((KP)&7)==0 ? v0[(KP)&31] : ((KP)&7)==1 ? v1[(KP)&31] : \
  ((KP)&7)==2 ? v2[(KP)&31] : ((KP)&7)==3 ? v3[(KP)&31] : \
  ((KP)&7)==4 ? v4[(KP)&31] : ((KP)&7)==5 ? v5[(KP)&31] : \
  ((KP)&7)==6 ? v6[(KP)&31] : v7[(KP)&31] )

// one elimination step, K literal
#define STEP(K) { \
  __syncthreads(); \
  if (8*R + 7 > (K)) { \
    const float ukk = ((const float*)urow[(K)&1])[(K)]; \
    const float rk = __builtin_amdgcn_rcpf(ukk); \
    const float4 ca = colbuf[(K)&1][2*R], cb = colbuf[(K)&1][2*R+1]; \
    const float m0 = ca.x*rk, m1 = ca.y*rk, m2 = ca.z*rk, m3 = ca.w*rk; \
    const float m4 = cb.x*rk, m5 = cb.y*rk, m6 = cb.z*rk, m7 = cb.w*rk; \
    if (32*G + 31 > (K)) { \
      const f32x32 uu = urow[(K)&1][G]; \
      v0 -= m0*uu; v1 -= m1*uu; v2 -= m2*uu; v3 -= m3*uu; \
      v4 -= m4*uu; v5 -= m5*uu; v6 -= m6*uu; v7 -= m7*uu; \
    } \
    if (R == (((K)+1) >> 3)) { \
      URSEL((K)+1) \
      if (G == (((K)+1) >> 5)) pivbuf[(K)+1] = PIVSEL((K)+1); \
    } \
    if (G == (((K)+1) >> 5)) { \
      colbuf[((K)+1)&1][2*R]   = make_float4(v0[((K)+1)&31], v1[((K)+1)&31], v2[((K)+1)&31], v3[((K)+1)&31]); \
      colbuf[((K)+1)&1][2*R+1] = make_float4(v4[((K)+1)&31], v5[((K)+1)&31], v6[((K)+1)&31], v7[((K)+1)&31]); \
    } \
  } \
}

#define S2(K)   STEP(K) STEP((K)+1)
#define S4(K)   S2(K)  S2((K)+2)
#define S8(K)   S4(K)  S4((K)+4)
#define S16(K)  S8(K)  S8((K)+8)
#define S32(K)  S16(K) S16((K)+16)
#define S64(K)  S32(K) S32((K)+32)
#define S128(K) S64(K) S64((K)+64)

// One workgroup (256 thr) per matrix. Thread (R,G) owns rows 8R..8R+7,
// cols 32G..32G+31, held in 8 named f32x32 vector registers (no allocas).
// Right-looking no-pivot LU; one barrier/step; colbuf (pivot column) and
// urow (pivot row) double-buffered in LDS, written at end of prior step.
__global__ __launch_bounds__(256, 1) void k_lu(const int* __restrict__ x) {
  __shared__ f32x32 urow[2][8];
  __shared__ float4 colbuf[2][64];
  __shared__ float  pivbuf[NN];
  __shared__ float  rowsum[NN];
  __shared__ float  psum[8][NN];
  __shared__ int    xs[NN];
  __shared__ float  red[4];

  const int t = threadIdx.x;
  const int R = t >> 3;   // row-group: rows 8R..8R+7 (wave = 64 contiguous rows)
  const int G = t & 7;    // col-group: cols 32G..32G+31
  const int m = blockIdx.x;

  if (m < BB) xs[t] = x[m*NN + t];
  __syncthreads();

  f32x32 v0, v1, v2, v3, v4, v5, v6, v7;
  float s0=0,s1=0,s2=0,s3=0,s4=0,s5=0,s6=0,s7=0;

  // ---- build: gather the 8x32 block; accumulate per-row partial sums ----
  {
    const int gi0 = 8*R;
    const int r0i=(gi0+1)&255, r1i=(gi0+2)&255, r2i=(gi0+3)&255, r3i=(gi0+4)&255;
    const int r4i=(gi0+5)&255, r5i=(gi0+6)&255, r6i=(gi0+7)&255, r7i=(gi0+8)&255;
    if (m < BB) {
      const float* Tb = &g_T[0][0];
      const float* b0 = Tb + 2*xs[r0i]*(NN*NN) + r0i;
      const float* b1 = Tb + 2*xs[r1i]*(NN*NN) + r1i;
      const float* b2 = Tb + 2*xs[r2i]*(NN*NN) + r2i;
      const float* b3 = Tb + 2*xs[r3i]*(NN*NN) + r3i;
      const float* b4 = Tb + 2*xs[r4i]*(NN*NN) + r4i;
      const float* b5 = Tb + 2*xs[r5i]*(NN*NN) + r5i;
      const float* b6 = Tb + 2*xs[r6i]*(NN*NN) + r6i;
      const float* b7 = Tb + 2*xs[r7i]*(NN*NN) + r7i;
      B32(BCOLT)
    } else {
      const float* b0 = g_Ws + r0i; const float* b1 = g_Ws + r1i;
      const float* b2 = g_Ws + r2i; const float* b3 = g_Ws + r3i;
      const float* b4 = g_Ws + r4i; const float* b5 = g_Ws + r5i;
      const float* b6 = g_Ws + r6i; const float* b7 = g_Ws + r7i;
      B32(BCOLW)
    }
  }
  *(float4*)&psum[G][8*R]   = make_float4(s0,s1,s2,s3);
  *(float4*)&psum[G][8*R+4] = make_float4(s4,s5,s6,s7);
  __syncthreads();

  // ---- per-row total: sum partials + original-col-0 term ----
  {
    const int r = t;
    const int ri = (r+1)&255;
    float tot = psum[0][r]+psum[1][r]+psum[2][r]+psum[3][r]
              + psum[4][r]+psum[5][r]+psum[6][r]+psum[7][r];
    float w0;
    if (m < BB) w0 = g_T[0][ (2*xs[ri] + xs[0])*(NN*NN) + ri ];
    else        w0 = g_Ws[ri];
    rowsum[r] = tot + w0;
  }
  __syncthreads();

  // ---- insert diagonal (literal positions per R&3 arm) ----
  if (G == (R >> 2)) {
    float4 ra = *(const float4*)&rowsum[8*R];
    float4 rb = *(const float4*)&rowsum[8*R+4];
    switch (R & 3) {
      case 0: v0[0] =ra.x; v1[1] =ra.y; v2[2] =ra.z; v3[3] =ra.w;
              v4[4] =rb.x; v5[5] =rb.y; v6[6] =rb.z; v7[7] =rb.w; break;
      case 1: v0[8] =ra.x; v1[9] =ra.y; v2[10]=ra.z; v3[11]=ra.w;
              v4[12]=rb.x; v5[13]=rb.y; v6[14]=rb.z; v7[15]=rb.w; break;
      case 2: v0[16]=ra.x; v1[17]=ra.y; v2[18]=ra.z; v3[19]=ra.w;
              v4[20]=rb.x; v5[21]=rb.y; v6[22]=rb.z; v7[23]=rb.w; break;
      default:v0[24]=ra.x; v1[25]=ra.y; v2[26]=ra.z; v3[27]=ra.w;
              v4[28]=rb.x; v5[29]=rb.y; v6[30]=rb.z; v7[31]=rb.w; break;
    }
  }
  // pad row 255 = e_255
  if (R == 31) {
    v7 = (f32x32)(0.0f);
    if (G == 7) v7[31] = 1.0f;
  }
  // initial broadcasts (buffers index 0)
  if (R == 0) {
    urow[0][G] = v0;
    if (G == 0) pivbuf[0] = v0[0];
  }
  if (G == 0) {
    colbuf[0][2*R]   = make_float4(v0[0], v1[0], v2[0], v3[0]);
    colbuf[0][2*R+1] = make_float4(v4[0], v5[0], v6[0], v7[0]);
  }

  // ---- 255 elimination steps ----
  S128(0) S64(128) S32(192) S16(224) S8(240) S4(248) S2(252) STEP(254)

  // ---- log|det| = sum log|u_kk| ----
  __syncthreads();
  float lg = logf(fabsf(pivbuf[t]));
  #pragma unroll
  for (int off = 32; off > 0; off >>= 1) lg += __shfl_down(lg, off, 64);
  if ((t & 63) == 0) red[t >> 6] = lg;
  __syncthreads();
  if (t == 0) g_ld[m] = red[0] + red[1] + red[2] + red[3];
}

__global__ void k_final(const int* __restrict__ x, float* __restrict__ out) {
  __shared__ float red[4];
  int b = blockIdx.x, t = threadIdx.x;
  int xv = x[b*NN + t];
  float lg = logf(g_V[t][xv]);
  #pragma unroll
  for (int off = 32; off > 0; off >>= 1) lg += __shfl_down(lg, off, 64);
  if ((t & 63) == 0) red[t >> 6] = lg;
  __syncthreads();
  if (t == 0) out[b] = (red[0] + red[1] + red[2] + red[3]) + g_ld[b] - g_ld[BB];
}

extern "C" void kernel_launch(void* const* d_in, const int* in_sizes, int n_in,
                              void* d_out, int out_size, void* d_ws, size_t ws_size,
                              hipStream_t stream) {
  const float* W   = (const float*)d_in[0];
  const float* lam = (const float*)d_in[1];
  const float* Vc  = (const float*)d_in[2];
  const int*   x   = (const int*)d_in[3];
  float* out = (float*)d_out;

  k_prep_v<<<dim3(1),    dim3(NN), 0, stream>>>(Vc);
  k_prep_T<<<dim3(NN),   dim3(NN), 0, stream>>>(W, lam);
  k_lu    <<<dim3(NMAT), dim3(NN), 0, stream>>>(x);
  k_final <<<dim3(BB),   dim3(NN), 0, stream>>>(x, out);
}

// Round 6
// 797.039 us; speedup vs baseline: 21.9692x; 21.9692x over previous
//
#include <hip/hip_runtime.h>
#include <math.h>

#define NN 256
#define BB 1024
#define NMAT 1025   // 1024 batch matrices + 1 for L0

typedef float f32x32 __attribute__((ext_vector_type(32)));

// Static device storage (rewritten every launch)
__device__ float g_T[4][NN*NN];      // T[c][j*256+i] = Ws(i,j)*E(i,j,a,b)/(V[i][a]V[j][b]), c=2a+b
__device__ float g_Ws[NN*NN];        // Ws[j*256+i] (symmetric)
__device__ float g_V[NN][2];
__device__ float g_ld[NMAT];

__device__ __forceinline__ float sigmf(float v) { return 1.0f / (1.0f + expf(-v)); }

__global__ void k_prep_v(const float* __restrict__ Vc) {
  int i = threadIdx.x;
  float a = sigmf(Vc[2*i]);
  float b = sigmf(Vc[2*i+1]);
  float s = a + b;
  g_V[i][0] = a / s;
  g_V[i][1] = b / s;
}

__global__ void k_prep_T(const float* __restrict__ W, const float* __restrict__ lam) {
  int j = blockIdx.x;
  int i = threadIdx.x;
  float vi0 = g_V[i][0], vi1 = g_V[i][1];
  float vj0 = g_V[j][0], vj1 = g_V[j][1];
  float ws;
  if (i > j)      ws = sigmf(W[i*NN + j]);
  else if (i < j) ws = sigmf(W[j*NN + i]);
  else            ws = 0.0f;
  g_Ws[j*NN + i] = ws;
  float s = sigmf(lam[i*NN + j]);
  float pi = vi0, pj = vj0;
  float lower = fmaxf(1e-7f, pi + pj - 1.0f);
  float upper = fminf(pi, pj);
  float P00 = lower + s * (upper - lower);
  float P01 = pi - P00;
  float P10 = pj - P00;
  float P11 = 1.0f - pi - pj + P00;
  if (i == j) { P00 = P01 = P10 = P11 = 0.0f; }
  P00 = fminf(fmaxf(P00, 0.0f), 1.0f);
  P01 = fminf(fmaxf(P01, 0.0f), 1.0f);
  P10 = fminf(fmaxf(P10, 0.0f), 1.0f);
  P11 = fminf(fmaxf(P11, 0.0f), 1.0f);
  int o = j*NN + i;
  g_T[0][o] = ws * P00 / (vi0 * vj0);
  g_T[1][o] = ws * P01 / (vi0 * vj1);
  g_T[2][o] = ws * P10 / (vi1 * vj0);
  g_T[3][o] = ws * P11 / (vi1 * vj1);
}

// ---------- macro helpers (all vector element indices are literals) ----------

// swizzled float-index of chunk c within group g (chunk = 4 floats, 16B)
#define UIDX(g_, c_) (((g_) << 5) + ((((c_) ^ (g_)) & 7) << 2))

// build one column (literal cc); batch path
#define BCOLT(cc) { \
  const int gcn = ((G << 5) + (cc) + 1) & 255; \
  const int off = xs[gcn]*(NN*NN) + (gcn << 8); \
  float w0 = b0[off], w1 = b1[off], w2 = b2[off], w3 = b3[off]; \
  if (((cc) == 31) && (G == 7)) { w0 = 0; w1 = 0; w2 = 0; w3 = 0; } \
  s0 += w0; s1 += w1; s2 += w2; s3 += w3; \
  v0[(cc)] = -w0; v1[(cc)] = -w1; v2[(cc)] = -w2; v3[(cc)] = -w3; }

// build one column (literal cc); L0 path
#define BCOLW(cc) { \
  const int gcn = ((G << 5) + (cc) + 1) & 255; \
  const int off = (gcn << 8); \
  float w0 = b0[off], w1 = b1[off], w2 = b2[off], w3 = b3[off]; \
  if (((cc) == 31) && (G == 7)) { w0 = 0; w1 = 0; w2 = 0; w3 = 0; } \
  s0 += w0; s1 += w1; s2 += w2; s3 += w3; \
  v0[(cc)] = -w0; v1[(cc)] = -w1; v2[(cc)] = -w2; v3[(cc)] = -w3; }

#define B4(M,c)  M(c) M((c)+1) M((c)+2) M((c)+3)
#define B16(M,c) B4(M,c) B4(M,(c)+4) B4(M,(c)+8) B4(M,(c)+12)
#define B32(M)   B16(M,0) B16(M,16)

// store vector vv as the u-row for step (K)+1 (buffer ((K)+1)&1), swizzled
#define STOREU_V(vv, K) { _Pragma("unroll") \
  for (int c_ = 0; c_ < 8; ++c_) { \
    *(float4*)&urow_f[((((K)+1) & 1) << 8) + UIDX(G, c_)] = \
      make_float4(vv[4*c_], vv[4*c_+1], vv[4*c_+2], vv[4*c_+3]); } }

#define STOREU(K) { \
  if      (((((K)+1)) & 3) == 0) { STOREU_V(v0, K) } \
  else if (((((K)+1)) & 3) == 1) { STOREU_V(v1, K) } \
  else if (((((K)+1)) & 3) == 2) { STOREU_V(v2, K) } \
  else                           { STOREU_V(v3, K) } }

#define PIVV(KP) ( (((KP) & 3) == 0) ? v0[(KP) & 31] : \
                   (((KP) & 3) == 1) ? v1[(KP) & 31] : \
                   (((KP) & 3) == 2) ? v2[(KP) & 31] : v3[(KP) & 31] )

// one elimination step, K literal
#define STEP(K) { \
  __syncthreads(); \
  if (4*R + 3 > (K)) { \
    const float ukk = urow_f[(((K) & 1) << 8) + UIDX(((K) >> 5), (((K) >> 2) & 7)) + ((K) & 3)]; \
    const float rk = __builtin_amdgcn_rcpf(ukk); \
    const float4 ca = colbuf[(K) & 1][R]; \
    const float m0 = ca.x*rk, m1 = ca.y*rk, m2 = ca.z*rk, m3 = ca.w*rk; \
    if ((G << 5) + 31 > (K)) { \
      f32x32 uu; \
      _Pragma("unroll") \
      for (int c_ = 0; c_ < 8; ++c_) { \
        float4 u4 = *(const float4*)&urow_f[(((K) & 1) << 8) + UIDX(G, c_)]; \
        uu[4*c_] = u4.x; uu[4*c_+1] = u4.y; uu[4*c_+2] = u4.z; uu[4*c_+3] = u4.w; \
      } \
      v0 -= m0*uu; v1 -= m1*uu; v2 -= m2*uu; v3 -= m3*uu; \
      if (R == (((K)+1) >> 2)) { STOREU(K) } \
      if (G == (((K)+1) >> 5)) { \
        colbuf[((K)+1) & 1][R] = make_float4(v0[((K)+1) & 31], v1[((K)+1) & 31], \
                                             v2[((K)+1) & 31], v3[((K)+1) & 31]); \
        if (R == (((K)+1) >> 2)) pivbuf[(K)+1] = PIVV((K)+1); \
      } \
    } \
  } \
}

#define S2(K)   STEP(K) STEP((K)+1)
#define S4(K)   S2(K)  S2((K)+2)
#define S8(K)   S4(K)  S4((K)+4)
#define S16(K)  S8(K)  S8((K)+8)
#define S32(K)  S16(K) S16((K)+16)
#define S64(K)  S32(K) S32((K)+32)
#define S128(K) S64(K) S64((K)+64)

// One workgroup (512 thr) per matrix. Thread (R = t>>3, G = t&7) owns rows
// 4R..4R+3, cols 32G..32G+31, in 4 named f32x32 SSA vectors (128 VGPRs data).
// Right-looking no-pivot LU; one barrier/step; colbuf (pivot column) and
// urow (pivot row, XOR-bank-swizzled) double-buffered in LDS.
__global__ __launch_bounds__(512, 2) void k_lu(const int* __restrict__ x) {
  __shared__ __align__(16) float urow_f[2*NN];
  __shared__ float4 colbuf[2][64];
  __shared__ float  pivbuf[NN];
  __shared__ float  rowsum[NN];
  __shared__ float  psum[8][NN];
  __shared__ int    xs[NN];
  __shared__ float  red[4];

  const int t = threadIdx.x;
  const int R = t >> 3;   // row-group: rows 4R..4R+3
  const int G = t & 7;    // col-group: cols 32G..32G+31
  const int m = blockIdx.x;

  if (m < BB && t < NN) xs[t] = x[m*NN + t];
  __syncthreads();

  f32x32 v0, v1, v2, v3;
  float s0 = 0, s1 = 0, s2 = 0, s3 = 0;

  // ---- build: gather 4x32 block; accumulate per-row partial sums ----
  {
    const int r0i = (4*R + 1) & 255, r1i = (4*R + 2) & 255;
    const int r2i = (4*R + 3) & 255, r3i = (4*R + 4) & 255;
    if (m < BB) {
      const float* Tb = &g_T[0][0];
      const float* b0 = Tb + 2*xs[r0i]*(NN*NN) + r0i;
      const float* b1 = Tb + 2*xs[r1i]*(NN*NN) + r1i;
      const float* b2 = Tb + 2*xs[r2i]*(NN*NN) + r2i;
      const float* b3 = Tb + 2*xs[r3i]*(NN*NN) + r3i;
      B32(BCOLT)
    } else {
      const float* b0 = g_Ws + r0i; const float* b1 = g_Ws + r1i;
      const float* b2 = g_Ws + r2i; const float* b3 = g_Ws + r3i;
      B32(BCOLW)
    }
  }
  *(float4*)&psum[G][4*R] = make_float4(s0, s1, s2, s3);
  __syncthreads();

  // ---- per-row total: sum 8 partials + original-col-0 term ----
  if (t < NN) {
    const int r = t;
    const int ri = (r + 1) & 255;
    float tot = psum[0][r] + psum[1][r] + psum[2][r] + psum[3][r]
              + psum[4][r] + psum[5][r] + psum[6][r] + psum[7][r];
    float w0;
    if (m < BB) w0 = g_T[0][(2*xs[ri] + xs[0])*(NN*NN) + ri];
    else        w0 = g_Ws[ri];
    rowsum[r] = tot + w0;
  }
  __syncthreads();

  // ---- insert diagonal (literal element positions per R&7 arm) ----
  if (G == (R >> 3)) {
    float4 ra = *(const float4*)&rowsum[4*R];
    switch (R & 7) {
      case 0: v0[0]  = ra.x; v1[1]  = ra.y; v2[2]  = ra.z; v3[3]  = ra.w; break;
      case 1: v0[4]  = ra.x; v1[5]  = ra.y; v2[6]  = ra.z; v3[7]  = ra.w; break;
      case 2: v0[8]  = ra.x; v1[9]  = ra.y; v2[10] = ra.z; v3[11] = ra.w; break;
      case 3: v0[12] = ra.x; v1[13] = ra.y; v2[14] = ra.z; v3[15] = ra.w; break;
      case 4: v0[16] = ra.x; v1[17] = ra.y; v2[18] = ra.z; v3[19] = ra.w; break;
      case 5: v0[20] = ra.x; v1[21] = ra.y; v2[22] = ra.z; v3[23] = ra.w; break;
      case 6: v0[24] = ra.x; v1[25] = ra.y; v2[26] = ra.z; v3[27] = ra.w; break;
      default:v0[28] = ra.x; v1[29] = ra.y; v2[30] = ra.z; v3[31] = ra.w; break;
    }
  }
  // pad row 255 = e_255
  if (R == 63) {
    v3 = (f32x32)(0.0f);
    if (G == 7) v3[31] = 1.0f;
  }
  // initial broadcasts into buffer 0 (K = -1 gives buffer ((K)+1)&1 = 0)
  if (R == 0) { STOREU_V(v0, -1) }
  if (G == 0) colbuf[0][R] = make_float4(v0[0], v1[0], v2[0], v3[0]);
  if (t == 0) pivbuf[0] = v0[0];

  // ---- 255 elimination steps ----
  S128(0) S64(128) S32(192) S16(224) S8(240) S4(248) S2(252) STEP(254)

  // ---- log|det| = sum log|u_kk| ----
  __syncthreads();
  if (t < NN) {
    float lg = logf(fabsf(pivbuf[t]));
    #pragma unroll
    for (int off = 32; off > 0; off >>= 1) lg += __shfl_down(lg, off, 64);
    if ((t & 63) == 0) red[t >> 6] = lg;
  }
  __syncthreads();
  if (t == 0) g_ld[m] = red[0] + red[1] + red[2] + red[3];
}

__global__ void k_final(const int* __restrict__ x, float* __restrict__ out) {
  __shared__ float red[4];
  int b = blockIdx.x, t = threadIdx.x;
  int xv = x[b*NN + t];
  float lg = logf(g_V[t][xv]);
  #pragma unroll
  for (int off = 32; off > 0; off >>= 1) lg += __shfl_down(lg, off, 64);
  if ((t & 63) == 0) red[t >> 6] = lg;
  __syncthreads();
  if (t == 0) out[b] = (red[0] + red[1] + red[2] + red[3]) + g_ld[b] - g_ld[BB];
}

extern "C" void kernel_launch(void* const* d_in, const int* in_sizes, int n_in,
                              void* d_out, int out_size, void* d_ws, size_t ws_size,
                              hipStream_t stream) {
  const float* W   = (const float*)d_in[0];
  const float* lam = (const float*)d_in[1];
  const float* Vc  = (const float*)d_in[2];
  const int*   x   = (const int*)d_in[3];
  float* out = (float*)d_out;

  k_prep_v<<<dim3(1),    dim3(NN), 0, stream>>>(Vc);
  k_prep_T<<<dim3(NN),   dim3(NN), 0, stream>>>(W, lam);
  k_lu    <<<dim3(NMAT), dim3(512), 0, stream>>>(x);
  k_final <<<dim3(BB),   dim3(NN), 0, stream>>>(x, out);
}